// Round 7
// baseline (239.206 us; speedup 1.0000x reference)
//
#include <hip/hip_runtime.h>
#include <float.h>
#include <math.h>

#define B_SZ   2048
#define D_DIM  256
#define P_DIM  4
#define N_TOT  4096        // 2*B
#define EPS_F  1e-8f
#define RPP    16          // rows per panel (block)
#define NBK    1024        // buckets per row histogram
#define BSCALE 256.0f      // bucket width 1/256; tie-approx err ~1.3e-2 << 0.146

typedef short  s16x8 __attribute__((ext_vector_type(8)));
typedef float  f32x4 __attribute__((ext_vector_type(4)));

__device__ __forceinline__ unsigned short f2bf(float x) {
    unsigned int b = __float_as_uint(x);
    b += 0x7FFFu + ((b >> 16) & 1u);        // RNE
    return (unsigned short)(b >> 16);
}

// ---------------- Kernel A: row-normalize features -> bf16 ----------------
__global__ __launch_bounds__(64) void normalize_kernel(
    const float* __restrict__ z_i, const float* __restrict__ z_j,
    unsigned short* __restrict__ fb)
{
    int row  = blockIdx.x;
    int lane = threadIdx.x;
    const float* src = (row < B_SZ) ? (z_i + (size_t)row * D_DIM)
                                    : (z_j + (size_t)(row - B_SZ) * D_DIM);
    float4 v = ((const float4*)src)[lane];
    float ss = v.x*v.x + v.y*v.y + v.z*v.z + v.w*v.w;
    #pragma unroll
    for (int off = 32; off > 0; off >>= 1)
        ss += __shfl_down(ss, off, 64);
    ss = __shfl(ss, 0, 64);
    float inv = 1.0f / sqrtf(ss);
    ushort4 o;
    o.x = f2bf(v.x * inv); o.y = f2bf(v.y * inv);
    o.z = f2bf(v.z * inv); o.w = f2bf(v.w * inv);
    ((ushort4*)(fb + (size_t)row * D_DIM))[lane] = o;
}

// ---------------- Kernel B (FUSED, single-pass): panel logits + dual histogram ----------------
// R6 counters: MfmaUtil 3.9% (MFMA is ~7us of 171), Occupancy 22.8% (grid 256 = 1
// block/CU, 8 waves), VGPR 60 < live set (compiler serialized the loop), 2 passes.
// This version:
//  - COUNT-HISTOGRAM trick: sum_j log(denom_j) = sum_bk cnt[bk]*log(CDF[bk]).
//    A second fp32 count histogram eliminates pass 2 (second GEMM + 16.7M logs).
//  - 1024-thread blocks: 16 waves/CU (4/SIMD) at the same grid=256 -> 2x TLP.
//  - __launch_bounds__(1024,4): VGPR cap 128 >= ~110 live set (a[8]+b[8]+Lr[4]).
//  - Bucket-swizzled hist layout addr(b)=(b&15)*64+(b>>4): lane L owns contiguous
//    buckets [16L,16L+16) at lane-stride-1 addresses -> conflict-free CDF phase;
//    CDF itself stays in registers (never written back). 3 barriers total.
__global__ __launch_bounds__(1024, 4) void panel_kernel(
    const unsigned short* __restrict__ fb,
    const float* __restrict__ physics_i, const float* __restrict__ physics_j,
    float* __restrict__ partial)
{
    __shared__ float hsum[RPP * NBK];        // 64 KB (bucket-swizzled)
    __shared__ float hcnt[RPP * NBK];        // 64 KB
    __shared__ float scr[16];

    int tid = threadIdx.x;
    int L   = tid & 63;
    int w   = tid >> 6;                      // 0..15
    int i0  = blockIdx.x * RPP;

    float4 z4 = {0.f, 0.f, 0.f, 0.f};
    #pragma unroll
    for (int t = 0; t < 4; ++t) {            // 4096 float4 per array / 1024 threads
        ((float4*)hsum)[tid + t * 1024] = z4;
        ((float4*)hcnt)[tid + t * 1024] = z4;
    }

    // A-fragments: lane holds panel row i0+(L&15), k = kc*32 + (L>>4)*8 .. +8
    // (fragment scheme correctness-proven in R6's passing kernel)
    s16x8 a[8];
    #pragma unroll
    for (int kc = 0; kc < 8; ++kc)
        a[kc] = *(const s16x8*)(fb + (size_t)(i0 + (L & 15)) * D_DIM
                                + kc * 32 + (L >> 4) * 8);

    // labels for this lane's 4 output rows (C row = (L>>4)*4 + q)
    float4 Lr[4];
    #pragma unroll
    for (int q = 0; q < 4; ++q) {
        int r = i0 + (L >> 4) * 4 + q;
        const float* p = (r < B_SZ) ? physics_i + (size_t)r * P_DIM
                                    : physics_j + (size_t)(r - B_SZ) * P_DIM;
        Lr[q] = *(const float4*)p;
    }

    __syncthreads();                         // B0: zeros visible

    // ---- single pass: 16 waves x 16 cols = 256 cols/iter, 16 iters ----
    float SL = 0.f;
    for (int ct = 0; ct < 16; ++ct) {
        int jc = ct * 256 + w * 16 + (L & 15);

        const unsigned short* bp = fb + (size_t)jc * D_DIM + (L >> 4) * 8;
        s16x8 b[8];
        #pragma unroll
        for (int kc = 0; kc < 8; ++kc)
            b[kc] = *(const s16x8*)(bp + kc * 32);
        const float* pj = (jc < B_SZ) ? physics_i + (size_t)jc * P_DIM
                                      : physics_j + (size_t)(jc - B_SZ) * P_DIM;
        float4 Lj = *(const float4*)pj;

        f32x4 acc0 = {0.f, 0.f, 0.f, 0.f};  // two chains: halve MFMA dep latency
        f32x4 acc1 = {0.f, 0.f, 0.f, 0.f};
        #pragma unroll
        for (int kc = 0; kc < 4; ++kc) {
            acc0 = __builtin_amdgcn_mfma_f32_16x16x32_bf16(a[2*kc],   b[2*kc],   acc0, 0, 0, 0);
            acc1 = __builtin_amdgcn_mfma_f32_16x16x32_bf16(a[2*kc+1], b[2*kc+1], acc1, 0, 0, 0);
        }

        #pragma unroll
        for (int q = 0; q < 4; ++q) {
            int rq = (L >> 4) * 4 + q;
            float logit = (acc0[q] + acc1[q]) * 0.5f;          // /TEMP
            float d = fabsf(Lr[q].x - Lj.x) + fabsf(Lr[q].y - Lj.y)
                    + fabsf(Lr[q].z - Lj.z) + fabsf(Lr[q].w - Lj.w);
            int bk = (int)(d * BSCALE); if (bk > NBK - 1) bk = NBK - 1;
            if (jc != i0 + rq) {
                int addr = (rq << 10) | ((bk & 15) << 6) | (bk >> 4);  // swizzled
                atomicAdd(&hsum[addr], __expf(logit));
                atomicAdd(&hcnt[addr], 1.0f);
                SL += logit;
            }
        }
    }
    __syncthreads();                         // B1: histograms complete

    // ---- wave w owns row w: register-resident suffix CDF + count-weighted logs ----
    float term = 0.f;
    {
        const float* vs = hsum + (w << 10);
        const float* cs = hcnt + (w << 10);
        float v[16];
        float fs = 0.f;
        #pragma unroll
        for (int k = 0; k < 16; ++k) {       // bucket b = 16L + k at addr k*64 + L
            v[k] = vs[k * 64 + L];           // lane-stride-1: conflict-free
            fs += v[k];
        }
        float s = fs;
        #pragma unroll
        for (int off = 1; off < 64; off <<= 1) {   // cross-lane suffix (incl. self)
            float u = __shfl_down(s, off, 64);
            if (L + off < 64) s += u;
        }
        float run = s - fs;                  // sum of buckets strictly above lane's range
        #pragma unroll
        for (int k = 15; k >= 0; --k) {
            run += v[k];                     // inclusive suffix = denom for bucket b
            term += cs[k * 64 + L] * __logf(run + EPS_F);
        }
    }

    // ---- block reduce of (term - SL) ----
    float acc = term - SL;
    #pragma unroll
    for (int off = 32; off > 0; off >>= 1)
        acc += __shfl_down(acc, off, 64);
    if (L == 0) scr[w] = acc;
    __syncthreads();                         // B2
    if (tid == 0) {
        float s = 0.f;
        #pragma unroll
        for (int w2 = 0; w2 < 16; ++w2) s += scr[w2];
        partial[blockIdx.x] = s;
    }
}

// ---------------- Kernel C: final reduce (256 panel partials) ----------------
__global__ __launch_bounds__(256) void final_kernel(
    const float* __restrict__ partial, float* __restrict__ out)
{
    __shared__ float red[4];
    int tid = threadIdx.x;
    float s = 0.f;
    for (int i = tid; i < N_TOT / RPP; i += 256) s += partial[i];
    #pragma unroll
    for (int off = 32; off > 0; off >>= 1)
        s += __shfl_down(s, off, 64);
    if ((tid & 63) == 0) red[tid >> 6] = s;
    __syncthreads();
    if (tid == 0) {
        double tot = (double)red[0] + red[1] + red[2] + red[3];
        out[0] = (float)(tot / ((double)N_TOT * (N_TOT - 1)));
    }
}

extern "C" void kernel_launch(void* const* d_in, const int* in_sizes, int n_in,
                              void* d_out, int out_size, void* d_ws, size_t ws_size,
                              hipStream_t stream)
{
    const float* z_i  = (const float*)d_in[0];
    const float* z_j  = (const float*)d_in[1];
    const float* ph_i = (const float*)d_in[2];
    const float* ph_j = (const float*)d_in[3];

    unsigned short* fb      = (unsigned short*)d_ws;                  // 2 MB bf16
    float*          partial = (float*)(fb + (size_t)N_TOT * D_DIM);   // 1 KB

    normalize_kernel<<<N_TOT, 64, 0, stream>>>(z_i, z_j, fb);
    panel_kernel<<<N_TOT / RPP, 1024, 0, stream>>>(fb, ph_i, ph_j, partial);
    final_kernel<<<1, 256, 0, stream>>>(partial, (float*)d_out);
}